// Round 4
// baseline (614.724 us; speedup 1.0000x reference)
//
#include <hip/hip_runtime.h>
#include <hip/hip_bf16.h>

using s8v = __attribute__((ext_vector_type(8))) short;   // 8 bf16 (4 VGPRs)
using f4v = __attribute__((ext_vector_type(4))) float;   // MFMA accumulator

__device__ __forceinline__ float bf2f(ushort v) { return __uint_as_float(((unsigned)v) << 16); }
__device__ __forceinline__ ushort f2bf(float x) {
  unsigned u = __float_as_uint(x);
  return (ushort)((u + 0x7fffu + ((u >> 16) & 1u)) >> 16);   // RNE, matches numpy
}

#define BSH 9                    // 512 nodes per bucket
#define NPB 512
#define MAXB 1024
#define CHUNK 4096

// ---------------- phase 1: bucket histogram ----------------

__global__ __launch_bounds__(256) void k_hist(const int* __restrict__ dst,
                                              int* __restrict__ bucketCnt, int E) {
  __shared__ int hh[MAXB];
  int t = threadIdx.x;
  for (int i = t; i < MAXB; i += 256) hh[i] = 0;
  __syncthreads();
  int base = blockIdx.x * CHUNK;
  #pragma unroll
  for (int k = 0; k < CHUNK / 256; ++k) {
    int e = base + k * 256 + t;
    if (e < E) atomicAdd(&hh[dst[e] >> BSH], 1);
  }
  __syncthreads();
  for (int i = t; i < MAXB; i += 256) {
    int c = hh[i];
    if (c) atomicAdd(&bucketCnt[i], c);
  }
}

// ---------------- phase 2: scan buckets -> base & cursor ----------------

__global__ __launch_bounds__(1024) void k_bscan(const int* __restrict__ bucketCnt,
                                                int* __restrict__ bucketBase,
                                                int* __restrict__ bucketCursor,
                                                int* __restrict__ row_ptr,
                                                int B, int N, int E) {
  __shared__ int sh[MAXB];
  int t = threadIdx.x;
  int v = (t < B) ? bucketCnt[t] : 0;
  sh[t] = v;
  __syncthreads();
  for (int off = 1; off < MAXB; off <<= 1) {
    int y = (t >= off) ? sh[t - off] : 0;
    __syncthreads();
    sh[t] += y;
    __syncthreads();
  }
  int excl = sh[t] - v;
  if (t < B) { bucketBase[t] = excl; bucketCursor[t] = excl; }
  if (t == 0) { bucketBase[B] = E; row_ptr[N] = E; }
}

// ---------------- phase 3: partition edges into bucket-grouped staging ----------------

__global__ __launch_bounds__(256) void k_part(
    const int* __restrict__ src, const int* __restrict__ dst,
    int* __restrict__ bucketCursor, int2* __restrict__ stag, int E)
{
  __shared__ int hh[MAXB];     // local hist
  __shared__ int sc[MAXB];     // local exclusive scan
  __shared__ int cur[MAXB];    // placement cursor
  __shared__ int gb[MAXB];     // global base for this block's run
  __shared__ int aux[256];
  __shared__ int2 pairs[CHUNK];

  int t = threadIdx.x;
  int base = blockIdx.x * CHUNK;
  int M = E - base; if (M > CHUNK) M = CHUNK;

  int es[CHUNK / 256], ed[CHUNK / 256];
  #pragma unroll
  for (int k = 0; k < CHUNK / 256; ++k) {
    int e = base + k * 256 + t;
    if (e < E) { es[k] = src[e]; ed[k] = dst[e]; } else { ed[k] = -1; }
  }

  for (int i = t; i < MAXB; i += 256) hh[i] = 0;
  __syncthreads();
  #pragma unroll
  for (int k = 0; k < CHUNK / 256; ++k)
    if (ed[k] >= 0) atomicAdd(&hh[ed[k] >> BSH], 1);
  __syncthreads();

  // exclusive scan of hh[0..MAXB) with 256 threads, 4 elems each
  int p0 = hh[4 * t + 0], p1 = hh[4 * t + 1], p2 = hh[4 * t + 2], p3 = hh[4 * t + 3];
  int psum = p0 + p1 + p2 + p3;
  aux[t] = psum;
  __syncthreads();
  for (int off = 1; off < 256; off <<= 1) {
    int y = (t >= off) ? aux[t - off] : 0;
    __syncthreads();
    aux[t] += y;
    __syncthreads();
  }
  int tb = aux[t] - psum;
  sc[4 * t + 0] = tb;
  sc[4 * t + 1] = tb + p0;
  sc[4 * t + 2] = tb + p0 + p1;
  sc[4 * t + 3] = tb + p0 + p1 + p2;
  __syncthreads();
  for (int i = t; i < MAXB; i += 256) cur[i] = sc[i];
  __syncthreads();

  // place pairs bucket-major into LDS
  #pragma unroll
  for (int k = 0; k < CHUNK / 256; ++k)
    if (ed[k] >= 0) {
      int b = ed[k] >> BSH;
      int pos = atomicAdd(&cur[b], 1);
      pairs[pos] = make_int2(es[k], ed[k]);
    }
  // reserve global runs
  for (int i = t; i < MAXB; i += 256) {
    int c = hh[i];
    if (c) gb[i] = atomicAdd(&bucketCursor[i], c);
  }
  __syncthreads();

  // write out: slot s of bucket b goes to stag[gb[b] + s - sc[b]]
  for (int s = t; s < M; s += 256) {
    int2 pr = pairs[s];
    int b = pr.y >> BSH;
    stag[gb[b] + s - sc[b]] = pr;
  }
}

// ---------------- phase 4: per-bucket CSR finalize ----------------
// One block per bucket; all scatter writes confined to a ~64KB csr window.

__global__ __launch_bounds__(512) void k_csr_bucket(
    const int2* __restrict__ stag, const int* __restrict__ bucketBase,
    int* __restrict__ row_ptr, int* __restrict__ csr_src, int N)
{
  __shared__ int dh[NPB], db[NPB], dc[NPB];
  int t = threadIdx.x;
  int b = blockIdx.x;
  int n0 = b << BSH;
  int nn = N - n0; if (nn > NPB) nn = NPB;
  int estart = bucketBase[b], eend = bucketBase[b + 1];

  dh[t] = 0;
  __syncthreads();
  for (int e = estart + t; e < eend; e += 512)
    atomicAdd(&dh[stag[e].y - n0], 1);
  __syncthreads();
  int v = dh[t];
  db[t] = v;
  __syncthreads();
  for (int off = 1; off < NPB; off <<= 1) {
    int y = (t >= off) ? db[t - off] : 0;
    __syncthreads();
    db[t] += y;
    __syncthreads();
  }
  int excl = db[t] - v;
  if (t < nn) row_ptr[n0 + t] = estart + excl;
  dc[t] = excl;
  __syncthreads();
  for (int e = estart + t; e < eend; e += 512) {
    int2 pr = stag[e];
    int d = pr.y - n0;
    int pos = estart + atomicAdd(&dc[d], 1);
    csr_src[pos] = pr.x;
  }
}

// ---------------- fp32 -> bf16 cast (8 elems/thread) ----------------

__global__ __launch_bounds__(256) void k_cast(const float* __restrict__ in,
                                              ushort* __restrict__ outb, int n8) {
  int i = blockIdx.x * 256 + threadIdx.x;
  if (i >= n8) return;
  const float4* in4 = (const float4*)in;
  float4 va = in4[2 * i], vb = in4[2 * i + 1];
  s8v w;
  w[0] = (short)f2bf(va.x); w[1] = (short)f2bf(va.y);
  w[2] = (short)f2bf(va.z); w[3] = (short)f2bf(va.w);
  w[4] = (short)f2bf(vb.x); w[5] = (short)f2bf(vb.y);
  w[6] = (short)f2bf(vb.z); w[7] = (short)f2bf(vb.w);
  ((s8v*)outb)[i] = w;
}

// ---------------- aggregation: wave-per-node, 8 edges / 16 lines in flight ----------------
// lane = 8*g + c; group g handles edge e+g; lane covers bf16 cols 8c..8c+7 (16B load).

__global__ __launch_bounds__(256) void k_agg_bf(
    const ushort* __restrict__ fb, const int* __restrict__ rp,
    const int* __restrict__ csrc, float* __restrict__ agg, int N)
{
  int lane = threadIdx.x & 63;
  int node = (blockIdx.x * 256 + threadIdx.x) >> 6;
  if (node >= N) return;
  int g  = lane >> 3;
  int c8 = (lane & 7) * 8;
  int e0 = rp[node], e1 = rp[node + 1];
  int len = e1 - e0;
  float a0=0.f,a1=0.f,a2=0.f,a3=0.f,a4=0.f,a5=0.f,a6=0.f,a7=0.f;
  int nfull = len >> 3;
  int e = e0;
  for (int it = 0; it < nfull; ++it, e += 8) {
    int s = csrc[e + g];
    s8v vv = *(const s8v*)(fb + (size_t)s * 64 + c8);
    a0 += bf2f((ushort)vv[0]); a1 += bf2f((ushort)vv[1]);
    a2 += bf2f((ushort)vv[2]); a3 += bf2f((ushort)vv[3]);
    a4 += bf2f((ushort)vv[4]); a5 += bf2f((ushort)vv[5]);
    a6 += bf2f((ushort)vv[6]); a7 += bf2f((ushort)vv[7]);
  }
  if (e + g < e1) {
    int s = csrc[e + g];
    s8v vv = *(const s8v*)(fb + (size_t)s * 64 + c8);
    a0 += bf2f((ushort)vv[0]); a1 += bf2f((ushort)vv[1]);
    a2 += bf2f((ushort)vv[2]); a3 += bf2f((ushort)vv[3]);
    a4 += bf2f((ushort)vv[4]); a5 += bf2f((ushort)vv[5]);
    a6 += bf2f((ushort)vv[6]); a7 += bf2f((ushort)vv[7]);
  }
  a0 += __shfl_xor(a0, 8); a0 += __shfl_xor(a0, 16); a0 += __shfl_xor(a0, 32);
  a1 += __shfl_xor(a1, 8); a1 += __shfl_xor(a1, 16); a1 += __shfl_xor(a1, 32);
  a2 += __shfl_xor(a2, 8); a2 += __shfl_xor(a2, 16); a2 += __shfl_xor(a2, 32);
  a3 += __shfl_xor(a3, 8); a3 += __shfl_xor(a3, 16); a3 += __shfl_xor(a3, 32);
  a4 += __shfl_xor(a4, 8); a4 += __shfl_xor(a4, 16); a4 += __shfl_xor(a4, 32);
  a5 += __shfl_xor(a5, 8); a5 += __shfl_xor(a5, 16); a5 += __shfl_xor(a5, 32);
  a6 += __shfl_xor(a6, 8); a6 += __shfl_xor(a6, 16); a6 += __shfl_xor(a6, 32);
  a7 += __shfl_xor(a7, 8); a7 += __shfl_xor(a7, 16); a7 += __shfl_xor(a7, 32);
  if (g == 0) {
    float inv = 1.f / (float)(len > 0 ? len : 1);
    float* orow = agg + (size_t)node * 64 + c8;
    float4 o0 = make_float4(a0 * inv, a1 * inv, a2 * inv, a3 * inv);
    float4 o1 = make_float4(a4 * inv, a5 * inv, a6 * inv, a7 * inv);
    *(float4*)(orow + 0) = o0;
    *(float4*)(orow + 4) = o1;
  }
}

// ---------------- transform: out = relu(f@Ws + agg@Wn + b); writes bf16 (+opt fp32) ----------------

__global__ __launch_bounds__(128) void k_xform(
    const float* __restrict__ feat, const float* __restrict__ agg,
    const float* __restrict__ Ws, const float* __restrict__ Wn,
    const float* __restrict__ bias, float* __restrict__ out32,
    ushort* __restrict__ outb, int N, int write32)
{
  __shared__ float sWsT[64 * 64];
  __shared__ float sWnT[64 * 64];
  __shared__ float sb[64];
  for (int idx = threadIdx.x; idx < 4096; idx += 128) {
    int k = idx >> 6, j = idx & 63;
    sWsT[j * 64 + k] = Ws[idx];
    sWnT[j * 64 + k] = Wn[idx];
  }
  if (threadIdx.x < 64) sb[threadIdx.x] = bias[threadIdx.x];
  __syncthreads();

  int i = blockIdx.x * 128 + threadIdx.x;
  if (i >= N) return;

  const float4* feat4 = (const float4*)feat;
  const float4* agg4  = (const float4*)agg;
  float f[64], nv[64];
  #pragma unroll
  for (int q = 0; q < 16; ++q) {
    float4 v = feat4[(size_t)i * 16 + q];
    f[4*q+0] = v.x; f[4*q+1] = v.y; f[4*q+2] = v.z; f[4*q+3] = v.w;
    float4 u = agg4[(size_t)i * 16 + q];
    nv[4*q+0] = u.x; nv[4*q+1] = u.y; nv[4*q+2] = u.z; nv[4*q+3] = u.w;
  }

  const float4* A4 = (const float4*)sWsT;
  const float4* B4 = (const float4*)sWnT;
  float* orow = out32 + (size_t)i * 64;
  ushort* brow = outb + (size_t)i * 64;
  #pragma unroll 1
  for (int jo = 0; jo < 8; ++jo) {
    float rr[8];
    #pragma unroll
    for (int jj = 0; jj < 8; ++jj) {
      int j = jo * 8 + jj;
      float acc = sb[j];
      #pragma unroll
      for (int q = 0; q < 16; ++q) {
        float4 w = A4[j * 16 + q];
        acc += f[4*q+0]*w.x + f[4*q+1]*w.y + f[4*q+2]*w.z + f[4*q+3]*w.w;
        float4 u = B4[j * 16 + q];
        acc += nv[4*q+0]*u.x + nv[4*q+1]*u.y + nv[4*q+2]*u.z + nv[4*q+3]*u.w;
      }
      rr[jj] = fmaxf(acc, 0.f);
    }
    if (write32) {
      float4 o0 = make_float4(rr[0], rr[1], rr[2], rr[3]);
      float4 o1 = make_float4(rr[4], rr[5], rr[6], rr[7]);
      *(float4*)(orow + jo * 8 + 0) = o0;
      *(float4*)(orow + jo * 8 + 4) = o1;
    }
    s8v pk;
    #pragma unroll
    for (int jj = 0; jj < 8; ++jj) pk[jj] = (short)f2bf(rr[jj]);
    *(s8v*)(brow + jo * 8) = pk;
  }
}

// ---------------- W1 -> transposed bf16, padded rows of 200 ----------------

__global__ __launch_bounds__(256) void k_prep_w1t(const float* __restrict__ W1,
                                                  ushort* __restrict__ w1t) {
  int idx = blockIdx.x * 256 + threadIdx.x;
  if (idx >= 64 * 200) return;
  int n = idx / 200, k = idx % 200;
  float v = (k < 192) ? W1[k * 64 + n] : 0.f;
  w1t[idx] = f2bf(v);
}

// ---------------- head via MFMA; all pair-row gathers hoisted before MFMA ----------------

__global__ __launch_bounds__(256) void k_head_mfma(
    const ushort* __restrict__ hb, const int* __restrict__ x1, const int* __restrict__ x2,
    const ushort* __restrict__ w1t, const float* __restrict__ bl1,
    const float* __restrict__ W2, const float* __restrict__ bl2,
    float* __restrict__ out, int P)
{
  __shared__ __align__(16) ushort sW[64 * 200];
  __shared__ float sW2[128];
  __shared__ float sb1[64];
  __shared__ float sb2[2];
  {
    const float4* srcv = (const float4*)w1t;
    float4* dstv = (float4*)sW;
    for (int i = threadIdx.x; i < 1600; i += 256) dstv[i] = srcv[i];
    if (threadIdx.x < 128) sW2[threadIdx.x] = W2[threadIdx.x];
    if (threadIdx.x < 64)  sb1[threadIdx.x] = bl1[threadIdx.x];
    if (threadIdx.x < 2)   sb2[threadIdx.x] = bl2[threadIdx.x];
  }
  __syncthreads();

  int lane = threadIdx.x & 63;
  int wid  = threadIdx.x >> 6;
  int wbase = blockIdx.x * 256 + wid * 64;
  if (wbase >= P) return;

  int lrow = lane & 15;
  int lkg  = lane >> 4;

  // hoist all 16 row-gathers (4 pt-tiles x 2 rows x 2 k-slices)
  int i1v[4], i2v[4];
  #pragma unroll
  for (int pt = 0; pt < 4; ++pt) {
    int p = wbase + pt * 16 + lrow;
    int pc = (p < P) ? p : (P - 1);
    i1v[pt] = x1[pc]; i2v[pt] = x2[pc];
  }
  s8v r1v[4][2], r2v[4][2];
  #pragma unroll
  for (int pt = 0; pt < 4; ++pt) {
    const ushort* r1 = hb + (size_t)i1v[pt] * 64 + lkg * 8;
    const ushort* r2 = hb + (size_t)i2v[pt] * 64 + lkg * 8;
    r1v[pt][0] = *(const s8v*)(r1);
    r1v[pt][1] = *(const s8v*)(r1 + 32);
    r2v[pt][0] = *(const s8v*)(r2);
    r2v[pt][1] = *(const s8v*)(r2 + 32);
  }

  f4v acc[4][4];
  #pragma unroll
  for (int a = 0; a < 4; ++a)
    #pragma unroll
    for (int b = 0; b < 4; ++b)
      acc[a][b] = (f4v){0.f, 0.f, 0.f, 0.f};

  #pragma unroll 1
  for (int pt = 0; pt < 4; ++pt) {
    s8v a3[2];
    #pragma unroll
    for (int ks = 0; ks < 2; ++ks) {
      s8v d;
      #pragma unroll
      for (int j = 0; j < 8; ++j) {
        float fa = bf2f((ushort)r1v[pt][ks][j]);
        float fb = bf2f((ushort)r2v[pt][ks][j]);
        d[j] = (short)f2bf(fabsf(fa - fb));
      }
      a3[ks] = d;
    }
    #pragma unroll
    for (int nt = 0; nt < 4; ++nt) {
      int n = nt * 16 + lrow;
      const ushort* bw = &sW[n * 200 + lkg * 8];
      #pragma unroll
      for (int ks = 0; ks < 2; ++ks) {
        s8v b1f = *(const s8v*)(bw + ks * 32 + 0);
        s8v b2f = *(const s8v*)(bw + ks * 32 + 64);
        s8v b3f = *(const s8v*)(bw + ks * 32 + 128);
        acc[pt][nt] = __builtin_amdgcn_mfma_f32_16x16x32_bf16(r1v[pt][ks], b1f, acc[pt][nt], 0, 0, 0);
        acc[pt][nt] = __builtin_amdgcn_mfma_f32_16x16x32_bf16(r2v[pt][ks], b2f, acc[pt][nt], 0, 0, 0);
        acc[pt][nt] = __builtin_amdgcn_mfma_f32_16x16x32_bf16(a3[ks],      b3f, acc[pt][nt], 0, 0, 0);
      }
    }
  }

  float b1v[4], w20v[4], w21v[4];
  #pragma unroll
  for (int nt = 0; nt < 4; ++nt) {
    int n = nt * 16 + lrow;
    b1v[nt] = sb1[n];
    w20v[nt] = sW2[2 * n + 0];
    w21v[nt] = sW2[2 * n + 1];
  }
  float bb0 = sb2[0], bb1 = sb2[1];
  #pragma unroll
  for (int pt = 0; pt < 4; ++pt) {
    #pragma unroll
    for (int r = 0; r < 4; ++r) {
      float p0 = 0.f, p1 = 0.f;
      #pragma unroll
      for (int nt = 0; nt < 4; ++nt) {
        float z = fmaxf(acc[pt][nt][r] + b1v[nt], 0.f);
        p0 += z * w20v[nt];
        p1 += z * w21v[nt];
      }
      p0 += __shfl_xor(p0, 1); p1 += __shfl_xor(p1, 1);
      p0 += __shfl_xor(p0, 2); p1 += __shfl_xor(p1, 2);
      p0 += __shfl_xor(p0, 4); p1 += __shfl_xor(p1, 4);
      p0 += __shfl_xor(p0, 8); p1 += __shfl_xor(p1, 8);
      int pair = wbase + pt * 16 + lkg * 4 + r;
      if (lrow == 0 && pair < P) {
        float2 o = make_float2(p0 + bb0, p1 + bb1);
        *(float2*)(out + 2 * (size_t)pair) = o;
      }
    }
  }
}

// ---------------- launch ----------------

extern "C" void kernel_launch(void* const* d_in, const int* in_sizes, int n_in,
                              void* d_out, int out_size, void* d_ws, size_t ws_size,
                              hipStream_t stream)
{
  (void)n_in; (void)out_size; (void)ws_size;
  const float* h   = (const float*)d_in[0];
  const int*   src = (const int*)d_in[1];
  const int*   dst = (const int*)d_in[2];
  const int*   x1  = (const int*)d_in[3];
  const int*   x2  = (const int*)d_in[4];
  const float* Ws0 = (const float*)d_in[5];
  const float* Wn0 = (const float*)d_in[6];
  const float* b0  = (const float*)d_in[7];
  const float* Ws1 = (const float*)d_in[8];
  const float* Wn1 = (const float*)d_in[9];
  const float* b1  = (const float*)d_in[10];
  const float* W1  = (const float*)d_in[11];
  const float* bl1 = (const float*)d_in[12];
  const float* W2  = (const float*)d_in[13];
  const float* bl2 = (const float*)d_in[14];

  const int N = in_sizes[0] / 64;
  const int E = in_sizes[1];
  const int P = in_sizes[3];
  const int B = (N + NPB - 1) >> BSH;
  float* out = (float*)d_out;

  char* ws = (char*)d_ws;
  size_t off = 0;
  auto carve = [&](size_t bytes) {
    char* p = ws + off;
    off = (off + bytes + 255) & ~(size_t)255;
    return p;
  };
  int*    row_ptr  = (int*)carve((size_t)(N + 1) * 4);
  int*    bucketCnt    = (int*)carve(MAXB * 4);
  int*    bucketBase   = (int*)carve((MAXB + 1) * 4);
  int*    bucketCursor = (int*)carve(MAXB * 4);
  int*    csr_src  = (int*)carve((size_t)E * 4);
  ushort* h_bf     = (ushort*)carve((size_t)N * 64 * 2);
  ushort* m1       = (ushort*)carve((size_t)N * 64 * 2);
  ushort* m2       = (ushort*)carve((size_t)N * 64 * 2);
  // staging aliases buf1: staging dead before first write of buf1
  size_t big = (size_t)N * 64 * 4;
  size_t stg = (size_t)E * 8;
  char*  un  = carve(big > stg ? big : stg);
  int2*  stag = (int2*)un;
  float* buf1 = (float*)un;
  float* aggf = (float*)carve((size_t)N * 64 * 4);
  ushort* w1t = (ushort*)carve(64 * 200 * 2);

  const int NCH = (E + CHUNK - 1) / CHUNK;

  hipMemsetAsync(bucketCnt, 0, MAXB * 4, stream);
  k_hist <<<NCH, 256, 0, stream>>>(dst, bucketCnt, E);
  k_bscan<<<1, MAXB, 0, stream>>>(bucketCnt, bucketBase, bucketCursor, row_ptr, B, N, E);
  k_part <<<NCH, 256, 0, stream>>>(src, dst, bucketCursor, stag, E);
  k_csr_bucket<<<B, NPB, 0, stream>>>(stag, bucketBase, row_ptr, csr_src, N);

  k_cast<<<(N * 64 / 8 + 255) / 256, 256, 0, stream>>>(h, h_bf, N * 64 / 8);
  k_prep_w1t<<<(64 * 200 + 255) / 256, 256, 0, stream>>>(W1, w1t);

  const int nbW = (N + 3) / 4;
  const int nbX = (N + 127) / 128;

  k_agg_bf<<<nbW, 256, 0, stream>>>(h_bf, row_ptr, csr_src, aggf, N);
  k_xform<<<nbX, 128, 0, stream>>>(h, aggf, Ws0, Wn0, b0, buf1, m1, N, 1);
  k_agg_bf<<<nbW, 256, 0, stream>>>(m1, row_ptr, csr_src, aggf, N);
  k_xform<<<nbX, 128, 0, stream>>>(buf1, aggf, Ws1, Wn1, b1, buf1, m2, N, 0);

  const int nbP = (P + 255) / 256;
  k_head_mfma<<<nbP, 256, 0, stream>>>(m2, x1, x2, w1t, bl1, W2, bl2, out, P);
}

// Round 5
// 307.958 us; speedup vs baseline: 1.9961x; 1.9961x over previous
//
#include <hip/hip_runtime.h>
#include <hip/hip_bf16.h>

using s8v = __attribute__((ext_vector_type(8))) short;   // 8 bf16 (4 VGPRs)
using f4v = __attribute__((ext_vector_type(4))) float;   // MFMA accumulator

__device__ __forceinline__ float bf2f(ushort v) { return __uint_as_float(((unsigned)v) << 16); }
__device__ __forceinline__ ushort f2bf(float x) {
  unsigned u = __float_as_uint(x);
  return (ushort)((u + 0x7fffu + ((u >> 16) & 1u)) >> 16);   // RNE, matches numpy
}

#define BSH 9                    // 512 nodes per bucket
#define NPB 512
#define MAXB 1024
#define CHUNK 4096

// ---------------- phase 1: bucket histogram ----------------

__global__ __launch_bounds__(256) void k_hist(const int* __restrict__ dst,
                                              int* __restrict__ bucketCnt, int E) {
  __shared__ int hh[MAXB];
  int t = threadIdx.x;
  for (int i = t; i < MAXB; i += 256) hh[i] = 0;
  __syncthreads();
  int base = blockIdx.x * CHUNK;
  #pragma unroll
  for (int k = 0; k < CHUNK / 256; ++k) {
    int e = base + k * 256 + t;
    if (e < E) atomicAdd(&hh[dst[e] >> BSH], 1);
  }
  __syncthreads();
  for (int i = t; i < MAXB; i += 256) {
    int c = hh[i];
    if (c) atomicAdd(&bucketCnt[i], c);
  }
}

// ---------------- phase 2: scan buckets -> base & cursor ----------------

__global__ __launch_bounds__(1024) void k_bscan(const int* __restrict__ bucketCnt,
                                                int* __restrict__ bucketBase,
                                                int* __restrict__ bucketCursor,
                                                int* __restrict__ row_ptr,
                                                int B, int N, int E) {
  __shared__ int sh[MAXB];
  int t = threadIdx.x;
  int v = (t < B) ? bucketCnt[t] : 0;
  sh[t] = v;
  __syncthreads();
  for (int off = 1; off < MAXB; off <<= 1) {
    int y = (t >= off) ? sh[t - off] : 0;
    __syncthreads();
    sh[t] += y;
    __syncthreads();
  }
  int excl = sh[t] - v;
  if (t < B) { bucketBase[t] = excl; bucketCursor[t] = excl; }
  if (t == 0) { bucketBase[B] = E; row_ptr[N] = E; }
}

// ---------------- phase 3: partition edges into bucket-grouped staging ----------------

__global__ __launch_bounds__(256) void k_part(
    const int* __restrict__ src, const int* __restrict__ dst,
    int* __restrict__ bucketCursor, int2* __restrict__ stag, int E)
{
  __shared__ int hh[MAXB];     // local hist
  __shared__ int sc[MAXB];     // local exclusive scan
  __shared__ int cur[MAXB];    // placement cursor
  __shared__ int gb[MAXB];     // global base for this block's run
  __shared__ int aux[256];
  __shared__ int2 pairs[CHUNK];

  int t = threadIdx.x;
  int base = blockIdx.x * CHUNK;
  int M = E - base; if (M > CHUNK) M = CHUNK;

  int es[CHUNK / 256], ed[CHUNK / 256];
  #pragma unroll
  for (int k = 0; k < CHUNK / 256; ++k) {
    int e = base + k * 256 + t;
    if (e < E) { es[k] = src[e]; ed[k] = dst[e]; } else { ed[k] = -1; }
  }

  for (int i = t; i < MAXB; i += 256) hh[i] = 0;
  __syncthreads();
  #pragma unroll
  for (int k = 0; k < CHUNK / 256; ++k)
    if (ed[k] >= 0) atomicAdd(&hh[ed[k] >> BSH], 1);
  __syncthreads();

  // exclusive scan of hh[0..MAXB) with 256 threads, 4 elems each
  int p0 = hh[4 * t + 0], p1 = hh[4 * t + 1], p2 = hh[4 * t + 2], p3 = hh[4 * t + 3];
  int psum = p0 + p1 + p2 + p3;
  aux[t] = psum;
  __syncthreads();
  for (int off = 1; off < 256; off <<= 1) {
    int y = (t >= off) ? aux[t - off] : 0;
    __syncthreads();
    aux[t] += y;
    __syncthreads();
  }
  int tb = aux[t] - psum;
  sc[4 * t + 0] = tb;
  sc[4 * t + 1] = tb + p0;
  sc[4 * t + 2] = tb + p0 + p1;
  sc[4 * t + 3] = tb + p0 + p1 + p2;
  __syncthreads();
  for (int i = t; i < MAXB; i += 256) cur[i] = sc[i];
  __syncthreads();

  // place pairs bucket-major into LDS
  #pragma unroll
  for (int k = 0; k < CHUNK / 256; ++k)
    if (ed[k] >= 0) {
      int b = ed[k] >> BSH;
      int pos = atomicAdd(&cur[b], 1);
      pairs[pos] = make_int2(es[k], ed[k]);
    }
  // reserve global runs
  for (int i = t; i < MAXB; i += 256) {
    int c = hh[i];
    if (c) gb[i] = atomicAdd(&bucketCursor[i], c);
  }
  __syncthreads();

  // write out: slot s of bucket b goes to stag[gb[b] + s - sc[b]]
  for (int s = t; s < M; s += 256) {
    int2 pr = pairs[s];
    int b = pr.y >> BSH;
    stag[gb[b] + s - sc[b]] = pr;
  }
}

// ---------------- phase 4: per-bucket CSR finalize ----------------
// One block per bucket; all scatter writes confined to a ~64KB csr window.

__global__ __launch_bounds__(512) void k_csr_bucket(
    const int2* __restrict__ stag, const int* __restrict__ bucketBase,
    int* __restrict__ row_ptr, int* __restrict__ csr_src, int N)
{
  __shared__ int dh[NPB], db[NPB], dc[NPB];
  int t = threadIdx.x;
  int b = blockIdx.x;
  int n0 = b << BSH;
  int nn = N - n0; if (nn > NPB) nn = NPB;
  int estart = bucketBase[b], eend = bucketBase[b + 1];

  dh[t] = 0;
  __syncthreads();
  for (int e = estart + t; e < eend; e += 512)
    atomicAdd(&dh[stag[e].y - n0], 1);
  __syncthreads();
  int v = dh[t];
  db[t] = v;
  __syncthreads();
  for (int off = 1; off < NPB; off <<= 1) {
    int y = (t >= off) ? db[t - off] : 0;
    __syncthreads();
    db[t] += y;
    __syncthreads();
  }
  int excl = db[t] - v;
  if (t < nn) row_ptr[n0 + t] = estart + excl;
  dc[t] = excl;
  __syncthreads();
  for (int e = estart + t; e < eend; e += 512) {
    int2 pr = stag[e];
    int d = pr.y - n0;
    int pos = estart + atomicAdd(&dc[d], 1);
    csr_src[pos] = pr.x;
  }
}

// ---------------- fp32 -> bf16 cast (8 elems/thread) ----------------

__global__ __launch_bounds__(256) void k_cast(const float* __restrict__ in,
                                              ushort* __restrict__ outb, int n8) {
  int i = blockIdx.x * 256 + threadIdx.x;
  if (i >= n8) return;
  const float4* in4 = (const float4*)in;
  float4 va = in4[2 * i], vb = in4[2 * i + 1];
  s8v w;
  w[0] = (short)f2bf(va.x); w[1] = (short)f2bf(va.y);
  w[2] = (short)f2bf(va.z); w[3] = (short)f2bf(va.w);
  w[4] = (short)f2bf(vb.x); w[5] = (short)f2bf(vb.y);
  w[6] = (short)f2bf(vb.z); w[7] = (short)f2bf(vb.w);
  ((s8v*)outb)[i] = w;
}

// ---------------- aggregation: wave-per-node, 8 edges / 16 lines in flight ----------------

__global__ __launch_bounds__(256) void k_agg_bf(
    const ushort* __restrict__ fb, const int* __restrict__ rp,
    const int* __restrict__ csrc, float* __restrict__ agg, int N)
{
  int lane = threadIdx.x & 63;
  int node = (blockIdx.x * 256 + threadIdx.x) >> 6;
  if (node >= N) return;
  int g  = lane >> 3;
  int c8 = (lane & 7) * 8;
  int e0 = rp[node], e1 = rp[node + 1];
  int len = e1 - e0;
  float a0=0.f,a1=0.f,a2=0.f,a3=0.f,a4=0.f,a5=0.f,a6=0.f,a7=0.f;
  int nfull = len >> 3;
  int e = e0;
  for (int it = 0; it < nfull; ++it, e += 8) {
    int s = csrc[e + g];
    s8v vv = *(const s8v*)(fb + (size_t)s * 64 + c8);
    a0 += bf2f((ushort)vv[0]); a1 += bf2f((ushort)vv[1]);
    a2 += bf2f((ushort)vv[2]); a3 += bf2f((ushort)vv[3]);
    a4 += bf2f((ushort)vv[4]); a5 += bf2f((ushort)vv[5]);
    a6 += bf2f((ushort)vv[6]); a7 += bf2f((ushort)vv[7]);
  }
  if (e + g < e1) {
    int s = csrc[e + g];
    s8v vv = *(const s8v*)(fb + (size_t)s * 64 + c8);
    a0 += bf2f((ushort)vv[0]); a1 += bf2f((ushort)vv[1]);
    a2 += bf2f((ushort)vv[2]); a3 += bf2f((ushort)vv[3]);
    a4 += bf2f((ushort)vv[4]); a5 += bf2f((ushort)vv[5]);
    a6 += bf2f((ushort)vv[6]); a7 += bf2f((ushort)vv[7]);
  }
  a0 += __shfl_xor(a0, 8); a0 += __shfl_xor(a0, 16); a0 += __shfl_xor(a0, 32);
  a1 += __shfl_xor(a1, 8); a1 += __shfl_xor(a1, 16); a1 += __shfl_xor(a1, 32);
  a2 += __shfl_xor(a2, 8); a2 += __shfl_xor(a2, 16); a2 += __shfl_xor(a2, 32);
  a3 += __shfl_xor(a3, 8); a3 += __shfl_xor(a3, 16); a3 += __shfl_xor(a3, 32);
  a4 += __shfl_xor(a4, 8); a4 += __shfl_xor(a4, 16); a4 += __shfl_xor(a4, 32);
  a5 += __shfl_xor(a5, 8); a5 += __shfl_xor(a5, 16); a5 += __shfl_xor(a5, 32);
  a6 += __shfl_xor(a6, 8); a6 += __shfl_xor(a6, 16); a6 += __shfl_xor(a6, 32);
  a7 += __shfl_xor(a7, 8); a7 += __shfl_xor(a7, 16); a7 += __shfl_xor(a7, 32);
  if (g == 0) {
    float inv = 1.f / (float)(len > 0 ? len : 1);
    float* orow = agg + (size_t)node * 64 + c8;
    float4 o0 = make_float4(a0 * inv, a1 * inv, a2 * inv, a3 * inv);
    float4 o1 = make_float4(a4 * inv, a5 * inv, a6 * inv, a7 * inv);
    *(float4*)(orow + 0) = o0;
    *(float4*)(orow + 4) = o1;
  }
}

// ---------------- transform: out = relu(f@Ws + agg@Wn + b); writes bf16 (+opt fp32) ----------------

__global__ __launch_bounds__(128) void k_xform(
    const float* __restrict__ feat, const float* __restrict__ agg,
    const float* __restrict__ Ws, const float* __restrict__ Wn,
    const float* __restrict__ bias, float* __restrict__ out32,
    ushort* __restrict__ outb, int N, int write32)
{
  __shared__ float sWsT[64 * 64];
  __shared__ float sWnT[64 * 64];
  __shared__ float sb[64];
  for (int idx = threadIdx.x; idx < 4096; idx += 128) {
    int k = idx >> 6, j = idx & 63;
    sWsT[j * 64 + k] = Ws[idx];
    sWnT[j * 64 + k] = Wn[idx];
  }
  if (threadIdx.x < 64) sb[threadIdx.x] = bias[threadIdx.x];
  __syncthreads();

  int i = blockIdx.x * 128 + threadIdx.x;
  if (i >= N) return;

  const float4* feat4 = (const float4*)feat;
  const float4* agg4  = (const float4*)agg;
  float f[64], nv[64];
  #pragma unroll
  for (int q = 0; q < 16; ++q) {
    float4 v = feat4[(size_t)i * 16 + q];
    f[4*q+0] = v.x; f[4*q+1] = v.y; f[4*q+2] = v.z; f[4*q+3] = v.w;
    float4 u = agg4[(size_t)i * 16 + q];
    nv[4*q+0] = u.x; nv[4*q+1] = u.y; nv[4*q+2] = u.z; nv[4*q+3] = u.w;
  }

  const float4* A4 = (const float4*)sWsT;
  const float4* B4 = (const float4*)sWnT;
  float* orow = out32 + (size_t)i * 64;
  ushort* brow = outb + (size_t)i * 64;
  #pragma unroll 1
  for (int jo = 0; jo < 8; ++jo) {
    float rr[8];
    #pragma unroll
    for (int jj = 0; jj < 8; ++jj) {
      int j = jo * 8 + jj;
      float acc = sb[j];
      #pragma unroll
      for (int q = 0; q < 16; ++q) {
        float4 w = A4[j * 16 + q];
        acc += f[4*q+0]*w.x + f[4*q+1]*w.y + f[4*q+2]*w.z + f[4*q+3]*w.w;
        float4 u = B4[j * 16 + q];
        acc += nv[4*q+0]*u.x + nv[4*q+1]*u.y + nv[4*q+2]*u.z + nv[4*q+3]*u.w;
      }
      rr[jj] = fmaxf(acc, 0.f);
    }
    if (write32) {
      float4 o0 = make_float4(rr[0], rr[1], rr[2], rr[3]);
      float4 o1 = make_float4(rr[4], rr[5], rr[6], rr[7]);
      *(float4*)(orow + jo * 8 + 0) = o0;
      *(float4*)(orow + jo * 8 + 4) = o1;
    }
    s8v pk;
    #pragma unroll
    for (int jj = 0; jj < 8; ++jj) pk[jj] = (short)f2bf(rr[jj]);
    *(s8v*)(brow + jo * 8) = pk;
  }
}

// ---------------- W1 -> transposed bf16, padded rows of 200 ----------------

__global__ __launch_bounds__(256) void k_prep_w1t(const float* __restrict__ W1,
                                                  ushort* __restrict__ w1t) {
  int idx = blockIdx.x * 256 + threadIdx.x;
  if (idx >= 64 * 200) return;
  int n = idx / 200, k = idx % 200;
  float v = (k < 192) ? W1[k * 64 + n] : 0.f;
  w1t[idx] = f2bf(v);
}

// ---------------- head via MFMA: 32 pairs/wave, ALL indices compile-time ----------------
// acc[2][4] = 32 VGPR; per-pt fragments have short live ranges. No runtime
// indexing into register arrays anywhere (rule #20).

__global__ __launch_bounds__(256) void k_head_mfma(
    const ushort* __restrict__ hb, const int* __restrict__ x1, const int* __restrict__ x2,
    const ushort* __restrict__ w1t, const float* __restrict__ bl1,
    const float* __restrict__ W2, const float* __restrict__ bl2,
    float* __restrict__ out, int P)
{
  __shared__ __align__(16) ushort sW[64 * 200];
  __shared__ float sW2[128];
  __shared__ float sb1[64];
  __shared__ float sb2[2];
  {
    const float4* srcv = (const float4*)w1t;
    float4* dstv = (float4*)sW;
    for (int i = threadIdx.x; i < 1600; i += 256) dstv[i] = srcv[i];
    if (threadIdx.x < 128) sW2[threadIdx.x] = W2[threadIdx.x];
    if (threadIdx.x < 64)  sb1[threadIdx.x] = bl1[threadIdx.x];
    if (threadIdx.x < 2)   sb2[threadIdx.x] = bl2[threadIdx.x];
  }
  __syncthreads();

  int lane = threadIdx.x & 63;
  int wid  = threadIdx.x >> 6;
  int wbase = blockIdx.x * 128 + wid * 32;   // 32 pairs per wave
  if (wbase >= P) return;

  int lrow = lane & 15;
  int lkg  = lane >> 4;

  f4v acc[2][4];
  #pragma unroll
  for (int a = 0; a < 2; ++a)
    #pragma unroll
    for (int b = 0; b < 4; ++b)
      acc[a][b] = (f4v){0.f, 0.f, 0.f, 0.f};

  #pragma unroll
  for (int pt = 0; pt < 2; ++pt) {
    int p = wbase + pt * 16 + lrow;
    int pc = (p < P) ? p : (P - 1);
    int i1 = x1[pc], i2 = x2[pc];
    const ushort* r1 = hb + (size_t)i1 * 64 + lkg * 8;
    const ushort* r2 = hb + (size_t)i2 * 64 + lkg * 8;
    s8v a1_0 = *(const s8v*)(r1);
    s8v a1_1 = *(const s8v*)(r1 + 32);
    s8v a2_0 = *(const s8v*)(r2);
    s8v a2_1 = *(const s8v*)(r2 + 32);
    s8v d0, d1;
    #pragma unroll
    for (int j = 0; j < 8; ++j) {
      d0[j] = (short)f2bf(fabsf(bf2f((ushort)a1_0[j]) - bf2f((ushort)a2_0[j])));
      d1[j] = (short)f2bf(fabsf(bf2f((ushort)a1_1[j]) - bf2f((ushort)a2_1[j])));
    }
    #pragma unroll
    for (int nt = 0; nt < 4; ++nt) {
      const ushort* bw = &sW[(nt * 16 + lrow) * 200 + lkg * 8];
      s8v b1_0 = *(const s8v*)(bw + 0);
      s8v b2_0 = *(const s8v*)(bw + 64);
      s8v b3_0 = *(const s8v*)(bw + 128);
      acc[pt][nt] = __builtin_amdgcn_mfma_f32_16x16x32_bf16(a1_0, b1_0, acc[pt][nt], 0, 0, 0);
      acc[pt][nt] = __builtin_amdgcn_mfma_f32_16x16x32_bf16(a2_0, b2_0, acc[pt][nt], 0, 0, 0);
      acc[pt][nt] = __builtin_amdgcn_mfma_f32_16x16x32_bf16(d0,   b3_0, acc[pt][nt], 0, 0, 0);
      s8v b1_1 = *(const s8v*)(bw + 32);
      s8v b2_1 = *(const s8v*)(bw + 96);
      s8v b3_1 = *(const s8v*)(bw + 160);
      acc[pt][nt] = __builtin_amdgcn_mfma_f32_16x16x32_bf16(a1_1, b1_1, acc[pt][nt], 0, 0, 0);
      acc[pt][nt] = __builtin_amdgcn_mfma_f32_16x16x32_bf16(a2_1, b2_1, acc[pt][nt], 0, 0, 0);
      acc[pt][nt] = __builtin_amdgcn_mfma_f32_16x16x32_bf16(d1,   b3_1, acc[pt][nt], 0, 0, 0);
    }
  }

  float b1v[4], w20v[4], w21v[4];
  #pragma unroll
  for (int nt = 0; nt < 4; ++nt) {
    int n = nt * 16 + lrow;
    b1v[nt] = sb1[n];
    w20v[nt] = sW2[2 * n + 0];
    w21v[nt] = sW2[2 * n + 1];
  }
  float bb0 = sb2[0], bb1 = sb2[1];
  #pragma unroll
  for (int pt = 0; pt < 2; ++pt) {
    #pragma unroll
    for (int r = 0; r < 4; ++r) {
      float p0 = 0.f, p1 = 0.f;
      #pragma unroll
      for (int nt = 0; nt < 4; ++nt) {
        float z = fmaxf(acc[pt][nt][r] + b1v[nt], 0.f);
        p0 += z * w20v[nt];
        p1 += z * w21v[nt];
      }
      p0 += __shfl_xor(p0, 1); p1 += __shfl_xor(p1, 1);
      p0 += __shfl_xor(p0, 2); p1 += __shfl_xor(p1, 2);
      p0 += __shfl_xor(p0, 4); p1 += __shfl_xor(p1, 4);
      p0 += __shfl_xor(p0, 8); p1 += __shfl_xor(p1, 8);
      int pair = wbase + pt * 16 + lkg * 4 + r;
      if (lrow == 0 && pair < P) {
        float2 o = make_float2(p0 + bb0, p1 + bb1);
        *(float2*)(out + 2 * (size_t)pair) = o;
      }
    }
  }
}

// ---------------- launch ----------------

extern "C" void kernel_launch(void* const* d_in, const int* in_sizes, int n_in,
                              void* d_out, int out_size, void* d_ws, size_t ws_size,
                              hipStream_t stream)
{
  (void)n_in; (void)out_size; (void)ws_size;
  const float* h   = (const float*)d_in[0];
  const int*   src = (const int*)d_in[1];
  const int*   dst = (const int*)d_in[2];
  const int*   x1  = (const int*)d_in[3];
  const int*   x2  = (const int*)d_in[4];
  const float* Ws0 = (const float*)d_in[5];
  const float* Wn0 = (const float*)d_in[6];
  const float* b0  = (const float*)d_in[7];
  const float* Ws1 = (const float*)d_in[8];
  const float* Wn1 = (const float*)d_in[9];
  const float* b1  = (const float*)d_in[10];
  const float* W1  = (const float*)d_in[11];
  const float* bl1 = (const float*)d_in[12];
  const float* W2  = (const float*)d_in[13];
  const float* bl2 = (const float*)d_in[14];

  const int N = in_sizes[0] / 64;
  const int E = in_sizes[1];
  const int P = in_sizes[3];
  const int B = (N + NPB - 1) >> BSH;
  float* out = (float*)d_out;

  char* ws = (char*)d_ws;
  size_t off = 0;
  auto carve = [&](size_t bytes) {
    char* p = ws + off;
    off = (off + bytes + 255) & ~(size_t)255;
    return p;
  };
  int*    row_ptr  = (int*)carve((size_t)(N + 1) * 4);
  int*    bucketCnt    = (int*)carve(MAXB * 4);
  int*    bucketBase   = (int*)carve((MAXB + 1) * 4);
  int*    bucketCursor = (int*)carve(MAXB * 4);
  int*    csr_src  = (int*)carve((size_t)E * 4);
  ushort* h_bf     = (ushort*)carve((size_t)N * 64 * 2);
  ushort* m1       = (ushort*)carve((size_t)N * 64 * 2);
  ushort* m2       = (ushort*)carve((size_t)N * 64 * 2);
  // staging aliases buf1: staging dead before first write of buf1
  size_t big = (size_t)N * 64 * 4;
  size_t stg = (size_t)E * 8;
  char*  un  = carve(big > stg ? big : stg);
  int2*  stag = (int2*)un;
  float* buf1 = (float*)un;
  float* aggf = (float*)carve((size_t)N * 64 * 4);
  ushort* w1t = (ushort*)carve(64 * 200 * 2);

  const int NCH = (E + CHUNK - 1) / CHUNK;

  hipMemsetAsync(bucketCnt, 0, MAXB * 4, stream);
  k_hist <<<NCH, 256, 0, stream>>>(dst, bucketCnt, E);
  k_bscan<<<1, MAXB, 0, stream>>>(bucketCnt, bucketBase, bucketCursor, row_ptr, B, N, E);
  k_part <<<NCH, 256, 0, stream>>>(src, dst, bucketCursor, stag, E);
  k_csr_bucket<<<B, NPB, 0, stream>>>(stag, bucketBase, row_ptr, csr_src, N);

  k_cast<<<(N * 64 / 8 + 255) / 256, 256, 0, stream>>>(h, h_bf, N * 64 / 8);
  k_prep_w1t<<<(64 * 200 + 255) / 256, 256, 0, stream>>>(W1, w1t);

  const int nbW = (N + 3) / 4;
  const int nbX = (N + 127) / 128;

  k_agg_bf<<<nbW, 256, 0, stream>>>(h_bf, row_ptr, csr_src, aggf, N);
  k_xform<<<nbX, 128, 0, stream>>>(h, aggf, Ws0, Wn0, b0, buf1, m1, N, 1);
  k_agg_bf<<<nbW, 256, 0, stream>>>(m1, row_ptr, csr_src, aggf, N);
  k_xform<<<nbX, 128, 0, stream>>>(buf1, aggf, Ws1, Wn1, b1, buf1, m2, N, 0);

  const int nbP = (P + 127) / 128;   // 128 pairs per block (32/wave)
  k_head_mfma<<<nbP, 256, 0, stream>>>(m2, x1, x2, w1t, bl1, W2, bl2, out, P);
}